// Round 5
// baseline (2260.985 us; speedup 1.0000x reference)
//
#include <hip/hip_runtime.h>
#include <hip/hip_bf16.h>

#define NN  20000
#define NE  320000
#define FIN 256
#define FH  512

typedef __attribute__((ext_vector_type(8))) short bf16x8;
typedef __attribute__((ext_vector_type(4))) float f32x4;
typedef __attribute__((ext_vector_type(4))) unsigned short u16x4;
typedef __attribute__((ext_vector_type(4))) unsigned int u32x4;

static __device__ __forceinline__ unsigned short f2b(float f) {
    union { float f; unsigned int i; } v; v.f = f;
    return (unsigned short)((v.i + 0x7fffu + ((v.i >> 16) & 1u)) >> 16);
}
static __device__ __forceinline__ f32x4 mfma16(bf16x8 a, bf16x8 b, f32x4 c) {
    return __builtin_amdgcn_mfma_f32_16x16x32_bf16(a, b, c, 0, 0, 0);
}
// 2x f32 -> packed bf16 pair (lowers to v_cvt_pk_bf16_f32), RNE
static __device__ __forceinline__ unsigned int cvtpk(float lo, float hi) {
    union { __hip_bfloat162 h; unsigned int u; } v;
    v.h = __float22bfloat162_rn(float2{lo, hi});
    return v.u;
}
static __device__ __forceinline__ u16x4 pack4(float a, float b, float c, float d) {
    union { u16x4 s; unsigned int u[2]; } v;
    v.u[0] = cvtpk(a, b); v.u[1] = cvtpk(c, d);
    return v.s;
}
static __device__ __forceinline__ bf16x8 cvt8(f32x4 a, f32x4 b) {
    u32x4 t;
    t[0] = cvtpk(a[0], a[1]);
    t[1] = cvtpk(a[2], a[3]);
    t[2] = cvtpk(b[0], b[1]);
    t[3] = cvtpk(b[2], b[3]);
    return __builtin_bit_cast(bf16x8, t);
}

// ------------------------------------------------- all-weights transpose+cvt
__global__ void prep_weights(const float* __restrict__ We1, const float* __restrict__ We2,
                             const float* __restrict__ Wn1, const float* __restrict__ Wn2,
                             unsigned short* __restrict__ W1T, unsigned short* __restrict__ W2T,
                             unsigned short* __restrict__ Wn1T, unsigned short* __restrict__ Wn2T) {
    const int m = blockIdx.x >> 7;
    const int t = blockIdx.x & 127;
    const float* src; unsigned short* dst; int R, C;
    if      (m == 0) { src = We1; dst = W1T;  R = 256; C = 512; }
    else if (m == 1) { src = We2; dst = W2T;  R = 512; C = 256; }
    else if (m == 2) { src = Wn1; dst = Wn1T; R = 256; C = 512; }
    else             { src = Wn2; dst = Wn2T; R = 512; C = 256; }
    __shared__ unsigned short tl[32][33];
    const int tx  = threadIdx.x & 31;
    const int tyb = threadIdx.x >> 5;
    const int cb = C >> 5;
    const int bx = t % cb, by = t / cb;
    #pragma unroll
    for (int j = 0; j < 4; ++j)
        tl[tyb * 4 + j][tx] = f2b(src[(size_t)(by * 32 + tyb * 4 + j) * C + bx * 32 + tx]);
    __syncthreads();
    #pragma unroll
    for (int j = 0; j < 4; ++j)
        dst[(size_t)(bx * 32 + tyb * 4 + j) * R + by * 32 + tx] = tl[tx][tyb * 4 + j];
}

// ------------------------------------------------- sort-by-dst prep
__global__ void hist_dst(const int* __restrict__ dstI, int* __restrict__ cnt) {
    int e = blockIdx.x * 256 + threadIdx.x;
    if (e < NE) atomicAdd(&cnt[dstI[e]], 1);
}

__global__ void scan_excl(const int* __restrict__ cnt, int* __restrict__ cursor) {
    __shared__ int c[NN];          // 80 KB
    __shared__ int s[1024];
    const int t = threadIdx.x;
    for (int i = t; i < NN; i += 1024) c[i] = cnt[i];
    __syncthreads();
    const int lo = t * 20;
    const int hi = (lo + 20 < NN) ? lo + 20 : NN;
    int sum = 0;
    for (int i = lo; i < hi; ++i) sum += c[i];
    s[t] = sum;
    __syncthreads();
    for (int off = 1; off < 1024; off <<= 1) {
        int v = (t >= off) ? s[t - off] : 0;
        __syncthreads();
        s[t] += v;
        __syncthreads();
    }
    int base = (t > 0) ? s[t - 1] : 0;
    for (int i = lo; i < hi; ++i) { int cv = c[i]; c[i] = base; base += cv; }
    __syncthreads();
    for (int i = t; i < NN; i += 1024) cursor[i] = c[i];
}

__global__ void scatter_perm(const int* __restrict__ dstI,
                             int* __restrict__ cursor, int* __restrict__ perm) {
    int e = blockIdx.x * 256 + threadIdx.x;
    if (e < NE) {
        int pos = atomicAdd(&cursor[dstI[e]], 1);
        perm[pos] = e;
    }
}

// ---------------------------------------------------------------- edge MLP
// 34 KB LDS union -> 4 blocks/CU (32 waves/CU). X staged once (bf16 LDS),
// then held in 128 VGPRs per wave; L1/L2 run in two 256-wide N/K halves so
// Hs is 32 KB; Msg scanned in two 32-edge windows (33.8 KB fp32).
__global__ void __launch_bounds__(512, 8)
gine_edge(const float* __restrict__ edge_feat,
          const float* __restrict__ node_feat,
          const int* __restrict__ srcI,
          const int* __restrict__ dstI,
          const int* __restrict__ perm,
          const unsigned short* __restrict__ W1T,   // [512,256] bf16 k-contig
          const float* __restrict__ b1,             // [512]
          const unsigned short* __restrict__ W2T,   // [256,512] bf16 k-contig
          const float* __restrict__ b2,             // [256]
          float* __restrict__ out_h)                // [NN,256] fp32 accum
{
    __shared__ union {
        unsigned short Xs[64 * 264];   // staged bf16 input (33.8 KB), dies after reg load
        unsigned short Hs[64 * 256];   // XOR-swizzled hidden K-half (32 KB)
        float          Msg[32 * 264];  // fp32 messages, 32-edge window (33.8 KB)
    } sh;
    __shared__ int snS[64], dnS[64], eS[64];

    const int tid  = threadIdx.x;
    const int wave = tid >> 6;       // 0..7
    const int lane = tid & 63;
    const int quad = lane >> 4;
    const int ln   = lane & 15;
    // XCD-affinity swizzle: 5000 blocks = 8 x 625.
    const int bs   = (blockIdx.x & 7) * 625 + (blockIdx.x >> 3);
    const int e0   = bs * 64;

    if (tid < 64) {
        const int e = perm[e0 + tid];
        eS[tid]  = e;
        snS[tid] = srcI[e];
        dnS[tid] = dstI[e];
    }
    __syncthreads();

    // ---- P0: stage gathered edge_feat rows -> bf16 LDS (once)
    #pragma unroll
    for (int it = 0; it < 4; ++it) {
        const int chunk = tid + it * 512;          // 2048 chunks of 8 elems
        const int row = chunk >> 5;
        const int c8  = (chunk & 31) << 3;
        const float* p = edge_feat + (size_t)eS[row] * FIN + c8;
        f32x4 o0 = *(const f32x4*)(p);
        f32x4 o1 = *(const f32x4*)(p + 4);
        *(bf16x8*)(&sh.Xs[row * 264 + c8]) = cvt8(o0, o1);
    }
    __syncthreads();

    // ---- P1: each wave loads its full X fragment set into registers
    bf16x8 xr[8][4];                               // 128 VGPRs
    #pragma unroll
    for (int ks = 0; ks < 8; ++ks)
        #pragma unroll
        for (int et = 0; et < 4; ++et)
            xr[ks][et] = *(const bf16x8*)(&sh.Xs[(et * 16 + ln) * 264 + quad * 8 + ks * 32]);
    __syncthreads();   // Xs dead; region becomes Hs

    const f32x4 zero4 = {0.f, 0.f, 0.f, 0.f};
    f32x4 acc2[2][4];                              // [n-tile][edge-tile], persists over halves
    #pragma unroll
    for (int nt = 0; nt < 2; ++nt)
        #pragma unroll
        for (int et = 0; et < 4; ++et) acc2[nt][et] = zero4;

    #pragma unroll
    for (int h = 0; h < 2; ++h) {
        // ---- L1 half: n in [h*256 + wave*32, +32)
        f32x4 acc1[2][4];
        #pragma unroll
        for (int nt = 0; nt < 2; ++nt)
            #pragma unroll
            for (int et = 0; et < 4; ++et) acc1[nt][et] = zero4;

        const unsigned short* wB = W1T + (size_t)(h * 256 + wave * 32 + ln) * FIN + quad * 8;
        #pragma unroll
        for (int ks = 0; ks < 8; ++ks) {
            bf16x8 w1[2];
            #pragma unroll
            for (int nt = 0; nt < 2; ++nt)
                w1[nt] = *(const bf16x8*)(wB + nt * 16 * FIN + ks * 32);
            #pragma unroll
            for (int nt = 0; nt < 2; ++nt)
                #pragma unroll
                for (int et = 0; et < 4; ++et)
                    acc1[nt][et] = mfma16(w1[nt], xr[ks][et], acc1[nt][et]);
        }

        // bias + relu -> packed bf16x4 -> swizzled Hs (local nl in [0,256))
        #pragma unroll
        for (int nt = 0; nt < 2; ++nt) {
            const int nl = wave * 32 + nt * 16 + quad * 4;
            const f32x4 b4 = *(const f32x4*)(b1 + h * 256 + nl);
            #pragma unroll
            for (int et = 0; et < 4; ++et) {
                const int edge = et * 16 + ln;
                u16x4 pk = pack4(fmaxf(acc1[nt][et][0] + b4[0], 0.f),
                                 fmaxf(acc1[nt][et][1] + b4[1], 0.f),
                                 fmaxf(acc1[nt][et][2] + b4[2], 0.f),
                                 fmaxf(acc1[nt][et][3] + b4[3], 0.f));
                *(u16x4*)(&sh.Hs[(edge << 8) + (((nl >> 3) ^ (edge & 7)) << 3) + (nl & 7)]) = pk;
            }
        }
        __syncthreads();   // Hs half complete

        // ---- L2 half accumulate: k in [h*256, h*256+256)
        const unsigned short* w2B = W2T + (size_t)(wave * 32 + ln) * FH + h * 256;
        #pragma unroll
        for (int ks = 0; ks < 8; ++ks) {
            const int kb = ks * 4 + quad;          // local k-block 0..31
            bf16x8 w2[2], hf[4];
            #pragma unroll
            for (int nt = 0; nt < 2; ++nt)
                w2[nt] = *(const bf16x8*)(w2B + nt * 16 * FH + kb * 8);
            #pragma unroll
            for (int et = 0; et < 4; ++et) {
                const int edge = et * 16 + ln;
                hf[et] = *(const bf16x8*)(&sh.Hs[(edge << 8) + ((kb ^ (edge & 7)) << 3)]);
            }
            #pragma unroll
            for (int nt = 0; nt < 2; ++nt)
                #pragma unroll
                for (int et = 0; et < 4; ++et)
                    acc2[nt][et] = mfma16(w2[nt], hf[et], acc2[nt][et]);
        }
        __syncthreads();   // Hs reads done (next half rewrites / Msg reuses)
    }

    // ---- epilogue: two 32-edge windows {Msg write, run-length scan}
    #pragma unroll
    for (int eh = 0; eh < 2; ++eh) {
        #pragma unroll
        for (int nt = 0; nt < 2; ++nt) {
            const int n0 = wave * 32 + nt * 16 + quad * 4;
            const f32x4 b4 = *(const f32x4*)(b2 + n0);
            #pragma unroll
            for (int el = 0; el < 2; ++el) {
                const int et = eh * 2 + el;
                const int edge = et * 16 + ln;
                const int sn = snS[edge];
                const f32x4 nf = *(const f32x4*)(node_feat + (size_t)sn * FIN + n0);
                f32x4 m;
                #pragma unroll
                for (int r = 0; r < 4; ++r)
                    m[r] = fmaxf(nf[r] + acc2[nt][et][r] + b4[r], 0.f);
                *(f32x4*)(&sh.Msg[(el * 16 + ln) * 264 + n0]) = m;
            }
        }
        __syncthreads();   // Msg window complete

        if (tid < 256) {
            const int col = tid;
            const int rA = eh * 32;
            const int dF = dnS[rA], dL = dnS[rA + 31];
            float run = sh.Msg[col];
            int cur = dF;
            #pragma unroll 4
            for (int row = 1; row < 32; ++row) {
                const int d = dnS[rA + row];
                if (d != cur) {
                    if (cur == dF || cur == dL)
                        atomicAdd(&out_h[(size_t)cur * FIN + col], run);
                    else
                        out_h[(size_t)cur * FIN + col] = run;
                    run = 0.f;
                    cur = d;
                }
                run += sh.Msg[row * 264 + col];
            }
            atomicAdd(&out_h[(size_t)cur * FIN + col], run);   // cur == dL
        }
        __syncthreads();   // Msg reads done before next window overwrite
    }
}

// ---------------------------------------------------------------- node MLP
// Same 34 KB structure: staged X -> regs, K-halved L2, no Msg/scan.
__global__ void __launch_bounds__(512, 8)
gine_node(const float* __restrict__ node_feat,
          const float* __restrict__ out_h,
          const unsigned short* __restrict__ W1T,   // [512,256] bf16
          const float* __restrict__ b1,
          const unsigned short* __restrict__ W2T,   // [256,512] bf16
          const float* __restrict__ b2,
          const float* __restrict__ eps,
          float* __restrict__ out)
{
    __shared__ union {
        unsigned short Xs[64 * 264];
        unsigned short Hs[64 * 256];
    } sh;

    const int tid  = threadIdx.x;
    const int wave = tid >> 6;
    const int lane = tid & 63;
    const int quad = lane >> 4;
    const int ln   = lane & 15;
    const int n0b  = blockIdx.x * 64;
    const float epsv = 1.0f + eps[0];

    // stage x = (1+eps)*node_feat + out_h  -> bf16 LDS
    #pragma unroll
    for (int it = 0; it < 4; ++it) {
        const int chunk = tid + it * 512;
        const int row = chunk >> 5;
        const int c8  = (chunk & 31) << 3;
        const int g   = n0b + row;
        bf16x8 pack = {0, 0, 0, 0, 0, 0, 0, 0};
        if (g < NN) {
            const float* pn = node_feat + (size_t)g * FIN + c8;
            const float* ph = out_h + (size_t)g * FIN + c8;
            f32x4 n0v = *(const f32x4*)(pn);
            f32x4 n1v = *(const f32x4*)(pn + 4);
            f32x4 h0v = *(const f32x4*)(ph);
            f32x4 h1v = *(const f32x4*)(ph + 4);
            f32x4 a, b;
            #pragma unroll
            for (int j = 0; j < 4; ++j) {
                a[j] = epsv * n0v[j] + h0v[j];
                b[j] = epsv * n1v[j] + h1v[j];
            }
            pack = cvt8(a, b);
        }
        *(bf16x8*)(&sh.Xs[row * 264 + c8]) = pack;
    }
    __syncthreads();

    // X -> registers
    bf16x8 xr[8][4];
    #pragma unroll
    for (int ks = 0; ks < 8; ++ks)
        #pragma unroll
        for (int et = 0; et < 4; ++et)
            xr[ks][et] = *(const bf16x8*)(&sh.Xs[(et * 16 + ln) * 264 + quad * 8 + ks * 32]);
    __syncthreads();

    const f32x4 zero4 = {0.f, 0.f, 0.f, 0.f};
    f32x4 acc2[2][4];
    #pragma unroll
    for (int nt = 0; nt < 2; ++nt)
        #pragma unroll
        for (int et = 0; et < 4; ++et) acc2[nt][et] = zero4;

    #pragma unroll
    for (int h = 0; h < 2; ++h) {
        f32x4 acc1[2][4];
        #pragma unroll
        for (int nt = 0; nt < 2; ++nt)
            #pragma unroll
            for (int et = 0; et < 4; ++et) acc1[nt][et] = zero4;

        const unsigned short* wB = W1T + (size_t)(h * 256 + wave * 32 + ln) * FIN + quad * 8;
        #pragma unroll
        for (int ks = 0; ks < 8; ++ks) {
            bf16x8 w1[2];
            #pragma unroll
            for (int nt = 0; nt < 2; ++nt)
                w1[nt] = *(const bf16x8*)(wB + nt * 16 * FIN + ks * 32);
            #pragma unroll
            for (int nt = 0; nt < 2; ++nt)
                #pragma unroll
                for (int et = 0; et < 4; ++et)
                    acc1[nt][et] = mfma16(w1[nt], xr[ks][et], acc1[nt][et]);
        }

        #pragma unroll
        for (int nt = 0; nt < 2; ++nt) {
            const int nl = wave * 32 + nt * 16 + quad * 4;
            const f32x4 b4 = *(const f32x4*)(b1 + h * 256 + nl);
            #pragma unroll
            for (int et = 0; et < 4; ++et) {
                const int edge = et * 16 + ln;
                u16x4 pk = pack4(fmaxf(acc1[nt][et][0] + b4[0], 0.f),
                                 fmaxf(acc1[nt][et][1] + b4[1], 0.f),
                                 fmaxf(acc1[nt][et][2] + b4[2], 0.f),
                                 fmaxf(acc1[nt][et][3] + b4[3], 0.f));
                *(u16x4*)(&sh.Hs[(edge << 8) + (((nl >> 3) ^ (edge & 7)) << 3) + (nl & 7)]) = pk;
            }
        }
        __syncthreads();

        const unsigned short* w2B = W2T + (size_t)(wave * 32 + ln) * FH + h * 256;
        #pragma unroll
        for (int ks = 0; ks < 8; ++ks) {
            const int kb = ks * 4 + quad;
            bf16x8 w2[2], hf[4];
            #pragma unroll
            for (int nt = 0; nt < 2; ++nt)
                w2[nt] = *(const bf16x8*)(w2B + nt * 16 * FH + kb * 8);
            #pragma unroll
            for (int et = 0; et < 4; ++et) {
                const int edge = et * 16 + ln;
                hf[et] = *(const bf16x8*)(&sh.Hs[(edge << 8) + ((kb ^ (edge & 7)) << 3)]);
            }
            #pragma unroll
            for (int nt = 0; nt < 2; ++nt)
                #pragma unroll
                for (int et = 0; et < 4; ++et)
                    acc2[nt][et] = mfma16(w2[nt], hf[et], acc2[nt][et]);
        }
        __syncthreads();
    }

    // C-write: 16-B vector stores
    #pragma unroll
    for (int nt = 0; nt < 2; ++nt) {
        const int n0 = wave * 32 + nt * 16 + quad * 4;
        const f32x4 b4 = *(const f32x4*)(b2 + n0);
        #pragma unroll
        for (int et = 0; et < 4; ++et) {
            const int g = n0b + et * 16 + ln;
            if (g < NN) {
                f32x4 o;
                #pragma unroll
                for (int r = 0; r < 4; ++r)
                    o[r] = acc2[nt][et][r] + b4[r];
                *(f32x4*)(out + (size_t)g * FIN + n0) = o;
            }
        }
    }
}

// ---------------------------------------------------------------- launch
extern "C" void kernel_launch(void* const* d_in, const int* in_sizes, int n_in,
                              void* d_out, int out_size, void* d_ws, size_t ws_size,
                              hipStream_t stream) {
    const float* node_feat = (const float*)d_in[0];
    const float* edge_feat = (const float*)d_in[1];
    const int* srcI = (const int*)d_in[2];
    const int* dstI = (const int*)d_in[3];
    const float* We1 = (const float*)d_in[4];
    const float* be1 = (const float*)d_in[5];
    const float* We2 = (const float*)d_in[6];
    const float* be2 = (const float*)d_in[7];
    const float* Wn1 = (const float*)d_in[8];
    const float* bn1 = (const float*)d_in[9];
    const float* Wn2 = (const float*)d_in[10];
    const float* bn2 = (const float*)d_in[11];
    const float* eps = (const float*)d_in[12];

    char* ws = (char*)d_ws;
    float* out_h = (float*)ws;                                  // 20,480,000 B
    unsigned short* W1T  = (unsigned short*)(ws + 20480000);    // 256 KB each
    unsigned short* W2T  = W1T + 131072;
    unsigned short* Wn1T = W2T + 131072;
    unsigned short* Wn2T = Wn1T + 131072;
    int* cnt    = (int*)(ws + 20480000 + 4 * 262144);           // 80 KB
    int* cursor = cnt + NN;                                     // 80 KB
    int* perm   = cursor + NN;                                  // 1.25 MB

    hipMemsetAsync(out_h, 0, (size_t)NN * FIN * sizeof(float), stream);
    hipMemsetAsync(cnt, 0, NN * sizeof(int), stream);

    prep_weights<<<512, 256, 0, stream>>>(We1, We2, Wn1, Wn2, W1T, W2T, Wn1T, Wn2T);

    hist_dst<<<(NE + 255) / 256, 256, 0, stream>>>(dstI, cnt);
    scan_excl<<<1, 1024, 0, stream>>>(cnt, cursor);
    scatter_perm<<<(NE + 255) / 256, 256, 0, stream>>>(dstI, cursor, perm);

    gine_edge<<<NE / 64, 512, 0, stream>>>(edge_feat, node_feat, srcI, dstI,
                                           perm, W1T, be1, W2T, be2, out_h);
    gine_node<<<(NN + 63) / 64, 512, 0, stream>>>(node_feat, out_h, Wn1T, bn1,
                                                  Wn2T, bn2, eps, (float*)d_out);
}

// Round 6
// 865.279 us; speedup vs baseline: 2.6130x; 2.6130x over previous
//
#include <hip/hip_runtime.h>
#include <hip/hip_bf16.h>

#define NN  20000
#define NE  320000
#define FIN 256
#define FH  512

typedef __attribute__((ext_vector_type(8))) short bf16x8;
typedef __attribute__((ext_vector_type(4))) float f32x4;
typedef __attribute__((ext_vector_type(4))) unsigned short u16x4;
typedef __attribute__((ext_vector_type(4))) unsigned int u32x4;

static __device__ __forceinline__ unsigned short f2b(float f) {
    union { float f; unsigned int i; } v; v.f = f;
    return (unsigned short)((v.i + 0x7fffu + ((v.i >> 16) & 1u)) >> 16);
}
static __device__ __forceinline__ f32x4 mfma16(bf16x8 a, bf16x8 b, f32x4 c) {
    return __builtin_amdgcn_mfma_f32_16x16x32_bf16(a, b, c, 0, 0, 0);
}
// 2x f32 -> packed bf16 pair (lowers to v_cvt_pk_bf16_f32), RNE
static __device__ __forceinline__ unsigned int cvtpk(float lo, float hi) {
    union { __hip_bfloat162 h; unsigned int u; } v;
    v.h = __float22bfloat162_rn(float2{lo, hi});
    return v.u;
}
static __device__ __forceinline__ u16x4 pack4(float a, float b, float c, float d) {
    union { u16x4 s; unsigned int u[2]; } v;
    v.u[0] = cvtpk(a, b); v.u[1] = cvtpk(c, d);
    return v.s;
}
static __device__ __forceinline__ bf16x8 cvt8(f32x4 a, f32x4 b) {
    u32x4 t;
    t[0] = cvtpk(a[0], a[1]);
    t[1] = cvtpk(a[2], a[3]);
    t[2] = cvtpk(b[0], b[1]);
    t[3] = cvtpk(b[2], b[3]);
    return __builtin_bit_cast(bf16x8, t);
}

// ------------------------------------------------- all-weights transpose+cvt
__global__ void prep_weights(const float* __restrict__ We1, const float* __restrict__ We2,
                             const float* __restrict__ Wn1, const float* __restrict__ Wn2,
                             unsigned short* __restrict__ W1T, unsigned short* __restrict__ W2T,
                             unsigned short* __restrict__ Wn1T, unsigned short* __restrict__ Wn2T) {
    const int m = blockIdx.x >> 7;
    const int t = blockIdx.x & 127;
    const float* src; unsigned short* dst; int R, C;
    if      (m == 0) { src = We1; dst = W1T;  R = 256; C = 512; }
    else if (m == 1) { src = We2; dst = W2T;  R = 512; C = 256; }
    else if (m == 2) { src = Wn1; dst = Wn1T; R = 256; C = 512; }
    else             { src = Wn2; dst = Wn2T; R = 512; C = 256; }
    __shared__ unsigned short tl[32][33];
    const int tx  = threadIdx.x & 31;
    const int tyb = threadIdx.x >> 5;
    const int cb = C >> 5;
    const int bx = t % cb, by = t / cb;
    #pragma unroll
    for (int j = 0; j < 4; ++j)
        tl[tyb * 4 + j][tx] = f2b(src[(size_t)(by * 32 + tyb * 4 + j) * C + bx * 32 + tx]);
    __syncthreads();
    #pragma unroll
    for (int j = 0; j < 4; ++j)
        dst[(size_t)(bx * 32 + tyb * 4 + j) * R + by * 32 + tx] = tl[tx][tyb * 4 + j];
}

// ------------------------------------------------- sort-by-dst prep
__global__ void hist_dst(const int* __restrict__ dstI, int* __restrict__ cnt) {
    int e = blockIdx.x * 256 + threadIdx.x;
    if (e < NE) atomicAdd(&cnt[dstI[e]], 1);
}

__global__ void scan_excl(const int* __restrict__ cnt, int* __restrict__ cursor) {
    __shared__ int c[NN];          // 80 KB
    __shared__ int s[1024];
    const int t = threadIdx.x;
    for (int i = t; i < NN; i += 1024) c[i] = cnt[i];
    __syncthreads();
    const int lo = t * 20;
    const int hi = (lo + 20 < NN) ? lo + 20 : NN;
    int sum = 0;
    for (int i = lo; i < hi; ++i) sum += c[i];
    s[t] = sum;
    __syncthreads();
    for (int off = 1; off < 1024; off <<= 1) {
        int v = (t >= off) ? s[t - off] : 0;
        __syncthreads();
        s[t] += v;
        __syncthreads();
    }
    int base = (t > 0) ? s[t - 1] : 0;
    for (int i = lo; i < hi; ++i) { int cv = c[i]; c[i] = base; base += cv; }
    __syncthreads();
    for (int i = t; i < NN; i += 1024) cursor[i] = c[i];
}

__global__ void scatter_perm(const int* __restrict__ dstI,
                             int* __restrict__ cursor, int* __restrict__ perm) {
    int e = blockIdx.x * 256 + threadIdx.x;
    if (e < NE) {
        int pos = atomicAdd(&cursor[dstI[e]], 1);
        perm[pos] = e;
    }
}

// ---------------------------------------------------------------- edge MLP
// R2-proven structure: 512 threads (8 waves) per 64-edge tile, 66 KB LDS,
// 2 blocks/CU (16 waves/CU, exactly at the 128-reg/wave occupancy point).
// Added: s_setprio(1) around the MFMA loops (T5) — 2 phase-skewed blocks/CU
// give the scheduler role diversity to arbitrate.
__global__ void __launch_bounds__(512, 4)
gine_edge(const float* __restrict__ edge_feat,
          const float* __restrict__ node_feat,
          const int* __restrict__ srcI,
          const int* __restrict__ dstI,
          const int* __restrict__ perm,
          const unsigned short* __restrict__ W1T,   // [512,256] bf16 k-contig
          const float* __restrict__ b1,             // [512]
          const unsigned short* __restrict__ W2T,   // [256,512] bf16 k-contig
          const float* __restrict__ b2,             // [256]
          float* __restrict__ out_h)                // [NN,256] fp32 accum
{
    __shared__ union {
        unsigned short Xs[64 * 264];   // staged bf16 input, +8 pad
        unsigned short Hs[64 * 512];   // XOR-swizzled hidden
        float          Msg[64 * 260];  // fp32 messages, +4 pad
    } sh;
    __shared__ int snS[64], dnS[64], eS[64];

    const int tid  = threadIdx.x;
    const int wave = tid >> 6;       // 0..7
    const int lane = tid & 63;
    const int quad = lane >> 4;
    const int ln   = lane & 15;
    const int bs   = (blockIdx.x & 7) * 625 + (blockIdx.x >> 3);
    const int e0   = bs * 64;

    if (tid < 64) {
        const int e = perm[e0 + tid];
        eS[tid]  = e;
        snS[tid] = srcI[e];
        dnS[tid] = dstI[e];
    }
    __syncthreads();

    // ---- stage gathered edge_feat rows -> bf16 LDS
    #pragma unroll
    for (int it = 0; it < 4; ++it) {
        const int chunk = tid + it * 512;          // 2048 chunks of 8 elems
        const int row = chunk >> 5;
        const int c8  = (chunk & 31) << 3;
        const float* p = edge_feat + (size_t)eS[row] * FIN + c8;
        f32x4 o0 = *(const f32x4*)(p);
        f32x4 o1 = *(const f32x4*)(p + 4);
        *(bf16x8*)(&sh.Xs[row * 264 + c8]) = cvt8(o0, o1);
    }
    __syncthreads();

    // ---- layer 1 (swapped): D1[n][edge]; 8 waves x 64-wide N slices
    f32x4 zero4 = {0.f, 0.f, 0.f, 0.f};
    f32x4 acc1[4][4];                              // [n-tile][edge-tile]
    #pragma unroll
    for (int nt = 0; nt < 4; ++nt)
        #pragma unroll
        for (int et = 0; et < 4; ++et) acc1[nt][et] = zero4;

    const unsigned short* wB = W1T + (wave * 64 + ln) * FIN + quad * 8;
    __builtin_amdgcn_s_setprio(1);
    #pragma unroll
    for (int ks = 0; ks < 8; ++ks) {
        bf16x8 w[4], x[4];
        #pragma unroll
        for (int nt = 0; nt < 4; ++nt)
            w[nt] = *(const bf16x8*)(wB + nt * 16 * FIN + ks * 32);
        #pragma unroll
        for (int et = 0; et < 4; ++et)
            x[et] = *(const bf16x8*)(&sh.Xs[(et * 16 + ln) * 264 + quad * 8 + ks * 32]);
        #pragma unroll
        for (int nt = 0; nt < 4; ++nt)
            #pragma unroll
            for (int et = 0; et < 4; ++et)
                acc1[nt][et] = mfma16(w[nt], x[et], acc1[nt][et]);
    }
    __builtin_amdgcn_s_setprio(0);
    __syncthreads();   // done reading Xs before overwriting Hs

    // bias + relu -> packed bf16x4 -> swizzled LDS
    #pragma unroll
    for (int nt = 0; nt < 4; ++nt) {
        const int n0 = wave * 64 + nt * 16 + quad * 4;     // 4 consecutive n
        const f32x4 b4 = *(const f32x4*)(b1 + n0);
        #pragma unroll
        for (int et = 0; et < 4; ++et) {
            const int edge = et * 16 + ln;
            u16x4 p = pack4(fmaxf(acc1[nt][et][0] + b4[0], 0.f),
                            fmaxf(acc1[nt][et][1] + b4[1], 0.f),
                            fmaxf(acc1[nt][et][2] + b4[2], 0.f),
                            fmaxf(acc1[nt][et][3] + b4[3], 0.f));
            *(u16x4*)(&sh.Hs[(edge << 9) + (((n0 >> 3) ^ (edge & 7)) << 3) + (n0 & 7)]) = p;
        }
    }
    __syncthreads();

    // ---- layer 2 (swapped): D2[n][edge]; 8 waves x 32-wide N slices
    f32x4 acc2[2][4];                              // [n-tile][edge-tile]
    #pragma unroll
    for (int nt = 0; nt < 2; ++nt)
        #pragma unroll
        for (int et = 0; et < 4; ++et) acc2[nt][et] = zero4;

    const unsigned short* w2B = W2T + (wave * 32 + ln) * FH;
    __builtin_amdgcn_s_setprio(1);
    #pragma unroll
    for (int ks = 0; ks < 16; ++ks) {
        const int kb = ks * 4 + quad;
        bf16x8 w[2], h[4];
        #pragma unroll
        for (int nt = 0; nt < 2; ++nt)
            w[nt] = *(const bf16x8*)(w2B + nt * 16 * FH + kb * 8);
        #pragma unroll
        for (int et = 0; et < 4; ++et) {
            const int edge = et * 16 + ln;
            h[et] = *(const bf16x8*)(&sh.Hs[(edge << 9) + ((kb ^ (edge & 7)) << 3)]);
        }
        #pragma unroll
        for (int nt = 0; nt < 2; ++nt)
            #pragma unroll
            for (int et = 0; et < 4; ++et)
                acc2[nt][et] = mfma16(w[nt], h[et], acc2[nt][et]);
    }
    __builtin_amdgcn_s_setprio(0);
    __syncthreads();   // done reading Hs before overwriting Msg

    // ---- epilogue 1: msg = relu(node_feat[src] + E) -> LDS (fp32)
    #pragma unroll
    for (int nt = 0; nt < 2; ++nt) {
        const int n0 = wave * 32 + nt * 16 + quad * 4;
        const f32x4 b4 = *(const f32x4*)(b2 + n0);
        #pragma unroll
        for (int et = 0; et < 4; ++et) {
            const int edge = et * 16 + ln;
            const int sn = snS[edge];
            const f32x4 nf = *(const f32x4*)(node_feat + (size_t)sn * FIN + n0);
            f32x4 m;
            #pragma unroll
            for (int r = 0; r < 4; ++r)
                m[r] = fmaxf(nf[r] + acc2[nt][et][r] + b4[r], 0.f);
            *(f32x4*)(&sh.Msg[edge * 260 + n0]) = m;
        }
    }
    __syncthreads();

    // ---- epilogue 2: run-length reduce over sorted dst rows; 512 threads =
    // 2 half-scans of 32 rows per column. Runs touching a half boundary use
    // atomicAdd (correct vs zero-init); interior runs are exclusive -> store.
    {
        const int col  = tid & 255;
        const int half = tid >> 8;
        const int rA   = half * 32;
        const int dF = dnS[rA], dL = dnS[rA + 31];
        float run = sh.Msg[rA * 260 + col];
        int cur = dF;
        #pragma unroll 4
        for (int row = rA + 1; row < rA + 32; ++row) {
            const int d = dnS[row];
            if (d != cur) {
                if (cur == dF || cur == dL)
                    atomicAdd(&out_h[(size_t)cur * FIN + col], run);
                else
                    out_h[(size_t)cur * FIN + col] = run;
                run = 0.f;
                cur = d;
            }
            run += sh.Msg[row * 260 + col];
        }
        atomicAdd(&out_h[(size_t)cur * FIN + col], run);   // cur == dL
    }
}

// ---------------------------------------------------------------- node MLP
__global__ void __launch_bounds__(512, 4)
gine_node(const float* __restrict__ node_feat,
          const float* __restrict__ out_h,
          const unsigned short* __restrict__ W1T,   // [512,256] bf16
          const float* __restrict__ b1,
          const unsigned short* __restrict__ W2T,   // [256,512] bf16
          const float* __restrict__ b2,
          const float* __restrict__ eps,
          float* __restrict__ out)
{
    __shared__ union {
        unsigned short Xs[64 * 264];
        unsigned short Hs[64 * 512];
    } sh;

    const int tid  = threadIdx.x;
    const int wave = tid >> 6;       // 0..7
    const int lane = tid & 63;
    const int quad = lane >> 4;
    const int ln   = lane & 15;
    const int n0b  = blockIdx.x * 64;
    const float epsv = 1.0f + eps[0];

    // stage x = (1+eps)*node_feat + out_h  -> bf16 LDS
    #pragma unroll
    for (int it = 0; it < 4; ++it) {
        const int chunk = tid + it * 512;
        const int row = chunk >> 5;
        const int c8  = (chunk & 31) << 3;
        const int g   = n0b + row;
        bf16x8 pack = {0, 0, 0, 0, 0, 0, 0, 0};
        if (g < NN) {
            const float* pn = node_feat + (size_t)g * FIN + c8;
            const float* ph = out_h + (size_t)g * FIN + c8;
            f32x4 n0v = *(const f32x4*)(pn);
            f32x4 n1v = *(const f32x4*)(pn + 4);
            f32x4 h0v = *(const f32x4*)(ph);
            f32x4 h1v = *(const f32x4*)(ph + 4);
            f32x4 a, b;
            #pragma unroll
            for (int j = 0; j < 4; ++j) {
                a[j] = epsv * n0v[j] + h0v[j];
                b[j] = epsv * n1v[j] + h1v[j];
            }
            pack = cvt8(a, b);
        }
        *(bf16x8*)(&sh.Xs[row * 264 + c8]) = pack;
    }
    __syncthreads();

    // ---- layer 1 (swapped)
    f32x4 zero4 = {0.f, 0.f, 0.f, 0.f};
    f32x4 acc1[4][4];
    #pragma unroll
    for (int nt = 0; nt < 4; ++nt)
        #pragma unroll
        for (int et = 0; et < 4; ++et) acc1[nt][et] = zero4;

    const unsigned short* wB = W1T + (wave * 64 + ln) * FIN + quad * 8;
    __builtin_amdgcn_s_setprio(1);
    #pragma unroll
    for (int ks = 0; ks < 8; ++ks) {
        bf16x8 w[4], xv[4];
        #pragma unroll
        for (int nt = 0; nt < 4; ++nt)
            w[nt] = *(const bf16x8*)(wB + nt * 16 * FIN + ks * 32);
        #pragma unroll
        for (int et = 0; et < 4; ++et)
            xv[et] = *(const bf16x8*)(&sh.Xs[(et * 16 + ln) * 264 + quad * 8 + ks * 32]);
        #pragma unroll
        for (int nt = 0; nt < 4; ++nt)
            #pragma unroll
            for (int et = 0; et < 4; ++et)
                acc1[nt][et] = mfma16(w[nt], xv[et], acc1[nt][et]);
    }
    __builtin_amdgcn_s_setprio(0);
    __syncthreads();

    #pragma unroll
    for (int nt = 0; nt < 4; ++nt) {
        const int n0 = wave * 64 + nt * 16 + quad * 4;
        const f32x4 b4 = *(const f32x4*)(b1 + n0);
        #pragma unroll
        for (int et = 0; et < 4; ++et) {
            const int edge = et * 16 + ln;
            u16x4 p = pack4(fmaxf(acc1[nt][et][0] + b4[0], 0.f),
                            fmaxf(acc1[nt][et][1] + b4[1], 0.f),
                            fmaxf(acc1[nt][et][2] + b4[2], 0.f),
                            fmaxf(acc1[nt][et][3] + b4[3], 0.f));
            *(u16x4*)(&sh.Hs[(edge << 9) + (((n0 >> 3) ^ (edge & 7)) << 3) + (n0 & 7)]) = p;
        }
    }
    __syncthreads();

    // ---- layer 2 (swapped)
    f32x4 acc2[2][4];
    #pragma unroll
    for (int nt = 0; nt < 2; ++nt)
        #pragma unroll
        for (int et = 0; et < 4; ++et) acc2[nt][et] = zero4;

    const unsigned short* w2B = W2T + (wave * 32 + ln) * FH;
    __builtin_amdgcn_s_setprio(1);
    #pragma unroll
    for (int ks = 0; ks < 16; ++ks) {
        const int kb = ks * 4 + quad;
        bf16x8 w[2], h[4];
        #pragma unroll
        for (int nt = 0; nt < 2; ++nt)
            w[nt] = *(const bf16x8*)(w2B + nt * 16 * FH + kb * 8);
        #pragma unroll
        for (int et = 0; et < 4; ++et) {
            const int edge = et * 16 + ln;
            h[et] = *(const bf16x8*)(&sh.Hs[(edge << 9) + ((kb ^ (edge & 7)) << 3)]);
        }
        #pragma unroll
        for (int nt = 0; nt < 2; ++nt)
            #pragma unroll
            for (int et = 0; et < 4; ++et)
                acc2[nt][et] = mfma16(w[nt], h[et], acc2[nt][et]);
    }
    __builtin_amdgcn_s_setprio(0);

    // C-write: 16-B vector stores
    #pragma unroll
    for (int nt = 0; nt < 2; ++nt) {
        const int n0 = wave * 32 + nt * 16 + quad * 4;
        const f32x4 b4 = *(const f32x4*)(b2 + n0);
        #pragma unroll
        for (int et = 0; et < 4; ++et) {
            const int g = n0b + et * 16 + ln;
            if (g < NN) {
                f32x4 o;
                #pragma unroll
                for (int r = 0; r < 4; ++r)
                    o[r] = acc2[nt][et][r] + b4[r];
                *(f32x4*)(out + (size_t)g * FIN + n0) = o;
            }
        }
    }
}

// ---------------------------------------------------------------- launch
extern "C" void kernel_launch(void* const* d_in, const int* in_sizes, int n_in,
                              void* d_out, int out_size, void* d_ws, size_t ws_size,
                              hipStream_t stream) {
    const float* node_feat = (const float*)d_in[0];
    const float* edge_feat = (const float*)d_in[1];
    const int* srcI = (const int*)d_in[2];
    const int* dstI = (const int*)d_in[3];
    const float* We1 = (const float*)d_in[4];
    const float* be1 = (const float*)d_in[5];
    const float* We2 = (const float*)d_in[6];
    const float* be2 = (const float*)d_in[7];
    const float* Wn1 = (const float*)d_in[8];
    const float* bn1 = (const float*)d_in[9];
    const float* Wn2 = (const float*)d_in[10];
    const float* bn2 = (const float*)d_in[11];
    const float* eps = (const float*)d_in[12];

    char* ws = (char*)d_ws;
    float* out_h = (float*)ws;                                  // 20,480,000 B
    unsigned short* W1T  = (unsigned short*)(ws + 20480000);    // 256 KB each
    unsigned short* W2T  = W1T + 131072;
    unsigned short* Wn1T = W2T + 131072;
    unsigned short* Wn2T = Wn1T + 131072;
    int* cnt    = (int*)(ws + 20480000 + 4 * 262144);           // 80 KB
    int* cursor = cnt + NN;                                     // 80 KB
    int* perm   = cursor + NN;                                  // 1.25 MB

    hipMemsetAsync(out_h, 0, (size_t)NN * FIN * sizeof(float), stream);
    hipMemsetAsync(cnt, 0, NN * sizeof(int), stream);

    prep_weights<<<512, 256, 0, stream>>>(We1, We2, Wn1, Wn2, W1T, W2T, Wn1T, Wn2T);

    hist_dst<<<(NE + 255) / 256, 256, 0, stream>>>(dstI, cnt);
    scan_excl<<<1, 1024, 0, stream>>>(cnt, cursor);
    scatter_perm<<<(NE + 255) / 256, 256, 0, stream>>>(dstI, cursor, perm);

    gine_edge<<<NE / 64, 512, 0, stream>>>(edge_feat, node_feat, srcI, dstI,
                                           perm, W1T, be1, W2T, be2, out_h);
    gine_node<<<(NN + 63) / 64, 512, 0, stream>>>(node_feat, out_h, Wn1T, bn1,
                                                  Wn2T, bn2, eps, (float*)d_out);
}

// Round 7
// 820.843 us; speedup vs baseline: 2.7545x; 1.0541x over previous
//
#include <hip/hip_runtime.h>
#include <hip/hip_bf16.h>

#define NN  20000
#define NE  320000
#define FIN 256
#define FH  512

typedef __attribute__((ext_vector_type(8))) short bf16x8;
typedef __attribute__((ext_vector_type(4))) float f32x4;
typedef __attribute__((ext_vector_type(4))) unsigned short u16x4;
typedef __attribute__((ext_vector_type(4))) unsigned int u32x4;

static __device__ __forceinline__ unsigned short f2b(float f) {
    union { float f; unsigned int i; } v; v.f = f;
    return (unsigned short)((v.i + 0x7fffu + ((v.i >> 16) & 1u)) >> 16);
}
static __device__ __forceinline__ f32x4 mfma16(bf16x8 a, bf16x8 b, f32x4 c) {
    return __builtin_amdgcn_mfma_f32_16x16x32_bf16(a, b, c, 0, 0, 0);
}
// 2x f32 -> packed bf16 pair (lowers to v_cvt_pk_bf16_f32), RNE
static __device__ __forceinline__ unsigned int cvtpk(float lo, float hi) {
    union { __hip_bfloat162 h; unsigned int u; } v;
    v.h = __float22bfloat162_rn(float2{lo, hi});
    return v.u;
}
static __device__ __forceinline__ u16x4 pack4(float a, float b, float c, float d) {
    union { u16x4 s; unsigned int u[2]; } v;
    v.u[0] = cvtpk(a, b); v.u[1] = cvtpk(c, d);
    return v.s;
}
static __device__ __forceinline__ bf16x8 cvt8(f32x4 a, f32x4 b) {
    u32x4 t;
    t[0] = cvtpk(a[0], a[1]);
    t[1] = cvtpk(a[2], a[3]);
    t[2] = cvtpk(b[0], b[1]);
    t[3] = cvtpk(b[2], b[3]);
    return __builtin_bit_cast(bf16x8, t);
}

// ---------------------------------------------- fragment-major weight prep
// For logical W^T[N][K] (n-major, k-contig), emit fragments: frag f =
// n_frag*(K/32)+ks is a 1KB blob; 16B chunk at (f*64+lane)*8 ushorts holds
// W^T[n_frag*16 + (lane&15)][ks*32 + (lane>>4)*8 + j], j=0..7.
// GEMM weight loads then read lane-contiguous 1KB segments (1 cache line
// set per instruction instead of a 16-line scatter).
__global__ void prep_weights(const float* __restrict__ We1, const float* __restrict__ We2,
                             const float* __restrict__ Wn1, const float* __restrict__ Wn2,
                             unsigned short* __restrict__ W1F, unsigned short* __restrict__ W2F,
                             unsigned short* __restrict__ Wn1F, unsigned short* __restrict__ Wn2F) {
    const int b = blockIdx.x;      // 1024 blocks x 64 threads
    const int m = b >> 8;
    const int f = b & 255;
    const float* src; unsigned short* dst; int N, K;
    if      (m == 0) { src = We1; dst = W1F;  N = 512; K = 256; }
    else if (m == 1) { src = We2; dst = W2F;  N = 256; K = 512; }
    else if (m == 2) { src = Wn1; dst = Wn1F; N = 512; K = 256; }
    else             { src = Wn2; dst = Wn2F; N = 256; K = 512; }
    const int KB  = K >> 5;
    const int nf  = f / KB, ks = f % KB;
    const int l   = threadIdx.x;
    const int quad = l >> 4, ln = l & 15;
    const int n  = nf * 16 + ln;
    const int k0 = ks * 32 + quad * 8;
    f32x4 a, c;
    #pragma unroll
    for (int j = 0; j < 4; ++j) {
        a[j] = src[(size_t)(k0 + j) * N + n];         // src is [K][N]
        c[j] = src[(size_t)(k0 + 4 + j) * N + n];
    }
    *(bf16x8*)(dst + ((size_t)f * 64 + l) * 8) = cvt8(a, c);
}

// ------------------------------------------------- sort-by-dst prep
__global__ void hist_dst(const int* __restrict__ dstI, int* __restrict__ cnt) {
    int e = blockIdx.x * 256 + threadIdx.x;
    if (e < NE) atomicAdd(&cnt[dstI[e]], 1);
}

__global__ void scan_excl(const int* __restrict__ cnt, int* __restrict__ cursor) {
    __shared__ int c[NN];          // 80 KB
    __shared__ int s[1024];
    const int t = threadIdx.x;
    for (int i = t; i < NN; i += 1024) c[i] = cnt[i];
    __syncthreads();
    const int lo = t * 20;
    const int hi = (lo + 20 < NN) ? lo + 20 : NN;
    int sum = 0;
    for (int i = lo; i < hi; ++i) sum += c[i];
    s[t] = sum;
    __syncthreads();
    for (int off = 1; off < 1024; off <<= 1) {
        int v = (t >= off) ? s[t - off] : 0;
        __syncthreads();
        s[t] += v;
        __syncthreads();
    }
    int base = (t > 0) ? s[t - 1] : 0;
    for (int i = lo; i < hi; ++i) { int cv = c[i]; c[i] = base; base += cv; }
    __syncthreads();
    for (int i = t; i < NN; i += 1024) cursor[i] = c[i];
}

__global__ void scatter_perm(const int* __restrict__ dstI,
                             int* __restrict__ cursor, int* __restrict__ perm) {
    int e = blockIdx.x * 256 + threadIdx.x;
    if (e < NE) {
        int pos = atomicAdd(&cursor[dstI[e]], 1);
        perm[pos] = e;
    }
}

// ---------------------------------------------------------------- edge MLP
// R6 structure + (1) fragment-major W loads (coalesced), (2) per-thread perm
// addressing in stage (no index barrier), (3) nf gather hoisted above L2
// MFMA (latency hidden in acc1-dead register window), setprio kept.
__global__ void __launch_bounds__(512, 4)
gine_edge(const float* __restrict__ edge_feat,
          const float* __restrict__ node_feat,
          const int* __restrict__ srcI,
          const int* __restrict__ dstI,
          const int* __restrict__ perm,
          const unsigned short* __restrict__ W1F,   // fragment-major [256 frags][1KB]
          const float* __restrict__ b1,             // [512]
          const unsigned short* __restrict__ W2F,   // fragment-major [256 frags][1KB]
          const float* __restrict__ b2,             // [256]
          float* __restrict__ out_h)                // [NN,256] fp32 accum
{
    __shared__ union {
        unsigned short Xs[64 * 264];   // staged bf16 input, +8 pad
        unsigned short Hs[64 * 512];   // XOR-swizzled hidden
        float          Msg[64 * 260];  // fp32 messages, +4 pad
    } sh;
    __shared__ int snS[64], dnS[64];

    const int tid  = threadIdx.x;
    const int wave = tid >> 6;       // 0..7
    const int lane = tid & 63;
    const int quad = lane >> 4;
    const int ln   = lane & 15;
    const int bs   = (blockIdx.x & 7) * 625 + (blockIdx.x >> 3);
    const int e0   = bs * 64;

    // ---- stage gathered edge_feat rows -> bf16 LDS (per-thread perm read,
    // no index barrier before stage issue)
    #pragma unroll
    for (int it = 0; it < 4; ++it) {
        const int chunk = tid + it * 512;          // 2048 chunks of 8 elems
        const int row = chunk >> 5;
        const int c8  = (chunk & 31) << 3;
        const int e   = perm[e0 + row];            // broadcast across 32 threads
        const float* p = edge_feat + (size_t)e * FIN + c8;
        f32x4 o0 = *(const f32x4*)(p);
        f32x4 o1 = *(const f32x4*)(p + 4);
        *(bf16x8*)(&sh.Xs[row * 264 + c8]) = cvt8(o0, o1);
    }
    if (tid < 64) {
        const int e = perm[e0 + tid];
        snS[tid] = srcI[e];
        dnS[tid] = dstI[e];
    }
    __syncthreads();

    // ---- layer 1 (swapped): D1[n][edge]; 8 waves x 64-wide N slices
    f32x4 zero4 = {0.f, 0.f, 0.f, 0.f};
    f32x4 acc1[4][4];                              // [n-tile][edge-tile]
    #pragma unroll
    for (int nt = 0; nt < 4; ++nt)
        #pragma unroll
        for (int et = 0; et < 4; ++et) acc1[nt][et] = zero4;

    __builtin_amdgcn_s_setprio(1);
    #pragma unroll
    for (int ks = 0; ks < 8; ++ks) {
        bf16x8 w[4], x[4];
        #pragma unroll
        for (int nt = 0; nt < 4; ++nt)            // frag (wave*4+nt, ks): 1KB lane-linear
            w[nt] = *(const bf16x8*)(W1F + (((wave * 4 + nt) * 8 + ks) * 64 + lane) * 8);
        #pragma unroll
        for (int et = 0; et < 4; ++et)
            x[et] = *(const bf16x8*)(&sh.Xs[(et * 16 + ln) * 264 + quad * 8 + ks * 32]);
        #pragma unroll
        for (int nt = 0; nt < 4; ++nt)
            #pragma unroll
            for (int et = 0; et < 4; ++et)
                acc1[nt][et] = mfma16(w[nt], x[et], acc1[nt][et]);
    }
    __builtin_amdgcn_s_setprio(0);
    __syncthreads();   // done reading Xs before overwriting Hs

    // bias + relu -> packed bf16x4 -> swizzled LDS
    #pragma unroll
    for (int nt = 0; nt < 4; ++nt) {
        const int n0 = wave * 64 + nt * 16 + quad * 4;     // 4 consecutive n
        const f32x4 b4 = *(const f32x4*)(b1 + n0);
        #pragma unroll
        for (int et = 0; et < 4; ++et) {
            const int edge = et * 16 + ln;
            u16x4 p = pack4(fmaxf(acc1[nt][et][0] + b4[0], 0.f),
                            fmaxf(acc1[nt][et][1] + b4[1], 0.f),
                            fmaxf(acc1[nt][et][2] + b4[2], 0.f),
                            fmaxf(acc1[nt][et][3] + b4[3], 0.f));
            *(u16x4*)(&sh.Hs[(edge << 9) + (((n0 >> 3) ^ (edge & 7)) << 3) + (n0 & 7)]) = p;
        }
    }
    __syncthreads();

    // ---- nf prefetch (T14): issue gathers now, consume after L2 MFMA.
    // acc1 is dead here, so the 32 VGPRs fit in its window.
    f32x4 nfr[2][4];
    #pragma unroll
    for (int nt = 0; nt < 2; ++nt) {
        const int n0 = wave * 32 + nt * 16 + quad * 4;
        #pragma unroll
        for (int et = 0; et < 4; ++et) {
            const int sn = snS[et * 16 + ln];
            nfr[nt][et] = *(const f32x4*)(node_feat + (size_t)sn * FIN + n0);
        }
    }

    // ---- layer 2 (swapped): D2[n][edge]; 8 waves x 32-wide N slices
    f32x4 acc2[2][4];                              // [n-tile][edge-tile]
    #pragma unroll
    for (int nt = 0; nt < 2; ++nt)
        #pragma unroll
        for (int et = 0; et < 4; ++et) acc2[nt][et] = zero4;

    __builtin_amdgcn_s_setprio(1);
    #pragma unroll
    for (int ks = 0; ks < 16; ++ks) {
        const int kb = ks * 4 + quad;
        bf16x8 w[2], h[4];
        #pragma unroll
        for (int nt = 0; nt < 2; ++nt)            // frag (wave*2+nt, ks)
            w[nt] = *(const bf16x8*)(W2F + (((wave * 2 + nt) * 16 + ks) * 64 + lane) * 8);
        #pragma unroll
        for (int et = 0; et < 4; ++et) {
            const int edge = et * 16 + ln;
            h[et] = *(const bf16x8*)(&sh.Hs[(edge << 9) + ((kb ^ (edge & 7)) << 3)]);
        }
        #pragma unroll
        for (int nt = 0; nt < 2; ++nt)
            #pragma unroll
            for (int et = 0; et < 4; ++et)
                acc2[nt][et] = mfma16(w[nt], h[et], acc2[nt][et]);
    }
    __builtin_amdgcn_s_setprio(0);
    __syncthreads();   // done reading Hs before overwriting Msg

    // ---- epilogue 1: msg = relu(nf + E) -> LDS (fp32), nf from prefetch regs
    #pragma unroll
    for (int nt = 0; nt < 2; ++nt) {
        const int n0 = wave * 32 + nt * 16 + quad * 4;
        const f32x4 b4 = *(const f32x4*)(b2 + n0);
        #pragma unroll
        for (int et = 0; et < 4; ++et) {
            const int edge = et * 16 + ln;
            f32x4 m;
            #pragma unroll
            for (int r = 0; r < 4; ++r)
                m[r] = fmaxf(nfr[nt][et][r] + acc2[nt][et][r] + b4[r], 0.f);
            *(f32x4*)(&sh.Msg[edge * 260 + n0]) = m;
        }
    }
    __syncthreads();

    // ---- epilogue 2: run-length reduce over sorted dst rows; 512 threads =
    // 2 half-scans of 32 rows per column. Runs touching a half boundary use
    // atomicAdd (correct vs zero-init); interior runs are exclusive -> store.
    {
        const int col  = tid & 255;
        const int half = tid >> 8;
        const int rA   = half * 32;
        const int dF = dnS[rA], dL = dnS[rA + 31];
        float run = sh.Msg[rA * 260 + col];
        int cur = dF;
        #pragma unroll 4
        for (int row = rA + 1; row < rA + 32; ++row) {
            const int d = dnS[row];
            if (d != cur) {
                if (cur == dF || cur == dL)
                    atomicAdd(&out_h[(size_t)cur * FIN + col], run);
                else
                    out_h[(size_t)cur * FIN + col] = run;
                run = 0.f;
                cur = d;
            }
            run += sh.Msg[row * 260 + col];
        }
        atomicAdd(&out_h[(size_t)cur * FIN + col], run);   // cur == dL
    }
}

// ---------------------------------------------------------------- node MLP
__global__ void __launch_bounds__(512, 4)
gine_node(const float* __restrict__ node_feat,
          const float* __restrict__ out_h,
          const unsigned short* __restrict__ W1F,   // fragment-major
          const float* __restrict__ b1,
          const unsigned short* __restrict__ W2F,   // fragment-major
          const float* __restrict__ b2,
          const float* __restrict__ eps,
          float* __restrict__ out)
{
    __shared__ union {
        unsigned short Xs[64 * 264];
        unsigned short Hs[64 * 512];
    } sh;

    const int tid  = threadIdx.x;
    const int wave = tid >> 6;       // 0..7
    const int lane = tid & 63;
    const int quad = lane >> 4;
    const int ln   = lane & 15;
    const int n0b  = blockIdx.x * 64;
    const float epsv = 1.0f + eps[0];

    // stage x = (1+eps)*node_feat + out_h  -> bf16 LDS
    #pragma unroll
    for (int it = 0; it < 4; ++it) {
        const int chunk = tid + it * 512;
        const int row = chunk >> 5;
        const int c8  = (chunk & 31) << 3;
        const int g   = n0b + row;
        bf16x8 pack = {0, 0, 0, 0, 0, 0, 0, 0};
        if (g < NN) {
            const float* pn = node_feat + (size_t)g * FIN + c8;
            const float* ph = out_h + (size_t)g * FIN + c8;
            f32x4 n0v = *(const f32x4*)(pn);
            f32x4 n1v = *(const f32x4*)(pn + 4);
            f32x4 h0v = *(const f32x4*)(ph);
            f32x4 h1v = *(const f32x4*)(ph + 4);
            f32x4 a, b;
            #pragma unroll
            for (int j = 0; j < 4; ++j) {
                a[j] = epsv * n0v[j] + h0v[j];
                b[j] = epsv * n1v[j] + h1v[j];
            }
            pack = cvt8(a, b);
        }
        *(bf16x8*)(&sh.Xs[row * 264 + c8]) = pack;
    }
    __syncthreads();

    // ---- layer 1 (swapped)
    f32x4 zero4 = {0.f, 0.f, 0.f, 0.f};
    f32x4 acc1[4][4];
    #pragma unroll
    for (int nt = 0; nt < 4; ++nt)
        #pragma unroll
        for (int et = 0; et < 4; ++et) acc1[nt][et] = zero4;

    __builtin_amdgcn_s_setprio(1);
    #pragma unroll
    for (int ks = 0; ks < 8; ++ks) {
        bf16x8 w[4], xv[4];
        #pragma unroll
        for (int nt = 0; nt < 4; ++nt)
            w[nt] = *(const bf16x8*)(W1F + (((wave * 4 + nt) * 8 + ks) * 64 + lane) * 8);
        #pragma unroll
        for (int et = 0; et < 4; ++et)
            xv[et] = *(const bf16x8*)(&sh.Xs[(et * 16 + ln) * 264 + quad * 8 + ks * 32]);
        #pragma unroll
        for (int nt = 0; nt < 4; ++nt)
            #pragma unroll
            for (int et = 0; et < 4; ++et)
                acc1[nt][et] = mfma16(w[nt], xv[et], acc1[nt][et]);
    }
    __builtin_amdgcn_s_setprio(0);
    __syncthreads();

    #pragma unroll
    for (int nt = 0; nt < 4; ++nt) {
        const int n0 = wave * 64 + nt * 16 + quad * 4;
        const f32x4 b4 = *(const f32x4*)(b1 + n0);
        #pragma unroll
        for (int et = 0; et < 4; ++et) {
            const int edge = et * 16 + ln;
            u16x4 p = pack4(fmaxf(acc1[nt][et][0] + b4[0], 0.f),
                            fmaxf(acc1[nt][et][1] + b4[1], 0.f),
                            fmaxf(acc1[nt][et][2] + b4[2], 0.f),
                            fmaxf(acc1[nt][et][3] + b4[3], 0.f));
            *(u16x4*)(&sh.Hs[(edge << 9) + (((n0 >> 3) ^ (edge & 7)) << 3) + (n0 & 7)]) = p;
        }
    }
    __syncthreads();

    // ---- layer 2 (swapped)
    f32x4 acc2[2][4];
    #pragma unroll
    for (int nt = 0; nt < 2; ++nt)
        #pragma unroll
        for (int et = 0; et < 4; ++et) acc2[nt][et] = zero4;

    __builtin_amdgcn_s_setprio(1);
    #pragma unroll
    for (int ks = 0; ks < 16; ++ks) {
        const int kb = ks * 4 + quad;
        bf16x8 w[2], h[4];
        #pragma unroll
        for (int nt = 0; nt < 2; ++nt)
            w[nt] = *(const bf16x8*)(W2F + (((wave * 2 + nt) * 16 + ks) * 64 + lane) * 8);
        #pragma unroll
        for (int et = 0; et < 4; ++et) {
            const int edge = et * 16 + ln;
            h[et] = *(const bf16x8*)(&sh.Hs[(edge << 9) + ((kb ^ (edge & 7)) << 3)]);
        }
        #pragma unroll
        for (int nt = 0; nt < 2; ++nt)
            #pragma unroll
            for (int et = 0; et < 4; ++et)
                acc2[nt][et] = mfma16(w[nt], h[et], acc2[nt][et]);
    }
    __builtin_amdgcn_s_setprio(0);

    // C-write: 16-B vector stores
    #pragma unroll
    for (int nt = 0; nt < 2; ++nt) {
        const int n0 = wave * 32 + nt * 16 + quad * 4;
        const f32x4 b4 = *(const f32x4*)(b2 + n0);
        #pragma unroll
        for (int et = 0; et < 4; ++et) {
            const int g = n0b + et * 16 + ln;
            if (g < NN) {
                f32x4 o;
                #pragma unroll
                for (int r = 0; r < 4; ++r)
                    o[r] = acc2[nt][et][r] + b4[r];
                *(f32x4*)(out + (size_t)g * FIN + n0) = o;
            }
        }
    }
}

// ---------------------------------------------------------------- launch
extern "C" void kernel_launch(void* const* d_in, const int* in_sizes, int n_in,
                              void* d_out, int out_size, void* d_ws, size_t ws_size,
                              hipStream_t stream) {
    const float* node_feat = (const float*)d_in[0];
    const float* edge_feat = (const float*)d_in[1];
    const int* srcI = (const int*)d_in[2];
    const int* dstI = (const int*)d_in[3];
    const float* We1 = (const float*)d_in[4];
    const float* be1 = (const float*)d_in[5];
    const float* We2 = (const float*)d_in[6];
    const float* be2 = (const float*)d_in[7];
    const float* Wn1 = (const float*)d_in[8];
    const float* bn1 = (const float*)d_in[9];
    const float* Wn2 = (const float*)d_in[10];
    const float* bn2 = (const float*)d_in[11];
    const float* eps = (const float*)d_in[12];

    char* ws = (char*)d_ws;
    float* out_h = (float*)ws;                                  // 20,480,000 B
    unsigned short* W1F  = (unsigned short*)(ws + 20480000);    // 256 KB each
    unsigned short* W2F  = W1F + 131072;
    unsigned short* Wn1F = W2F + 131072;
    unsigned short* Wn2F = Wn1F + 131072;
    int* cnt    = (int*)(ws + 20480000 + 4 * 262144);           // 80 KB
    int* cursor = cnt + NN;                                     // 80 KB
    int* perm   = cursor + NN;                                  // 1.25 MB

    hipMemsetAsync(out_h, 0, (size_t)NN * FIN * sizeof(float), stream);
    hipMemsetAsync(cnt, 0, NN * sizeof(int), stream);

    prep_weights<<<1024, 64, 0, stream>>>(We1, We2, Wn1, Wn2, W1F, W2F, Wn1F, Wn2F);

    hist_dst<<<(NE + 255) / 256, 256, 0, stream>>>(dstI, cnt);
    scan_excl<<<1, 1024, 0, stream>>>(cnt, cursor);
    scatter_perm<<<(NE + 255) / 256, 256, 0, stream>>>(dstI, cursor, perm);

    gine_edge<<<NE / 64, 512, 0, stream>>>(edge_feat, node_feat, srcI, dstI,
                                           perm, W1F, be1, W2F, be2, out_h);
    gine_node<<<(NN + 63) / 64, 512, 0, stream>>>(node_feat, out_h, Wn1F, bn1,
                                                  Wn2F, bn2, eps, (float*)d_out);
}